// Round 5
// baseline (35.587 us; speedup 1.0000x reference)
//
#include <hip/hip_runtime.h>

// Median blur 3x3, zero padding, lower median (== true median for 9 elems).
// x: (16, 3, 512, 512) float32 contiguous. Out same shape/dtype.
//
// R5: ROWS=16 per thread in TWO stages (10-row preload -> outputs 0..7,
// then 8 more rows reusing 2 boundary rows -> outputs 8..15). Vertical
// read amplification drops 1.25x -> 1.125x while peak live registers stay
// ~60 data regs (< 128 VGPR step -> 4 waves/SIMD). sched_barrier between
// stages keeps the compiler from hoisting stage-2 loads.

typedef float vf4 __attribute__((ext_vector_type(4)));

__device__ __forceinline__ void s2(float& a, float& b) {
    float t = fminf(a, b);
    b = fmaxf(a, b);
    a = t;
}
__device__ __forceinline__ float max3(float a, float b, float c) {
    return fmaxf(fmaxf(a, b), c);
}
__device__ __forceinline__ float min3(float a, float b, float c) {
    return fminf(fminf(a, b), c);
}
__device__ __forceinline__ float med3(float a, float b, float c) {
    return fmaxf(fminf(a, b), fminf(fmaxf(a, b), c));
}

__device__ __forceinline__ void load_row(float (&d)[6], const float* __restrict__ plane,
                                         int rr, int c0) {
    if (rr >= 0 && rr < 512) {
        const float* p = plane + rr * 512 + c0;
        vf4 v = *reinterpret_cast<const vf4*>(p);
        d[1] = v.x; d[2] = v.y; d[3] = v.z; d[4] = v.w;
        d[0] = (c0 > 0)       ? p[-1] : 0.0f;
        d[5] = (c0 + 4 < 512) ? p[4]  : 0.0f;
    } else {
        d[0] = d[1] = d[2] = 0.0f;
        d[3] = d[4] = d[5] = 0.0f;
    }
}

// Compute one 4-wide median row from 3 stacked 6-wide rows; NT-store it.
__device__ __forceinline__ void emit_row(const float (&ra)[6], const float (&rb)[6],
                                         const float (&rc)[6], float* __restrict__ po) {
    float lo[6], mi[6], hi[6];
#pragma unroll
    for (int j = 0; j < 6; ++j) {
        float a = ra[j], b = rb[j], c = rc[j];
        s2(b, c); s2(a, c); s2(a, b);
        lo[j] = a; mi[j] = b; hi[j] = c;
    }
    vf4 o;
    o.x = med3(max3(lo[0], lo[1], lo[2]), med3(mi[0], mi[1], mi[2]), min3(hi[0], hi[1], hi[2]));
    o.y = med3(max3(lo[1], lo[2], lo[3]), med3(mi[1], mi[2], mi[3]), min3(hi[1], hi[2], hi[3]));
    o.z = med3(max3(lo[2], lo[3], lo[4]), med3(mi[2], mi[3], mi[4]), min3(hi[2], hi[3], hi[4]));
    o.w = med3(max3(lo[3], lo[4], lo[5]), med3(mi[3], mi[4], mi[5]), min3(hi[3], hi[4], hi[5]));
    __builtin_nontemporal_store(o, reinterpret_cast<vf4*>(po));
}

constexpr int ROWS = 16;  // output rows per thread (two stages of 8)

__global__ __launch_bounds__(256) void median_blur_kernel(
        const float* __restrict__ x, float* __restrict__ out) {
    constexpr int W = 512, H = 512, W4 = W / 4;   // 128 groups/row
    constexpr int RB = H / ROWS;                  // 32 row-blocks

    // Bijective XCD-chunked swizzle (gridDim.x == 768, divisible by 8):
    // consecutive bids (vertical neighbors) land on the same XCD's L2.
    int cpx = gridDim.x >> 3;
    int bid = (blockIdx.x & 7) * cpx + (blockIdx.x >> 3);

    int gid = bid * blockDim.x + threadIdx.x;
    int w4 = gid & (W4 - 1);
    int rb = (gid >> 7) & (RB - 1);
    int bc = gid >> 12;

    const float* plane = x + (size_t)bc * H * W;
    float* oplane = out + (size_t)bc * H * W;
    int c0 = w4 * 4;
    int h0 = rb * ROWS;

    // ---- Stage 1: rows h0-1 .. h0+8 (10 rows), outputs h0 .. h0+7 ----
    float r[10][6];
#pragma unroll
    for (int i = 0; i < 10; ++i) load_row(r[i], plane, h0 - 1 + i, c0);

#pragma unroll
    for (int i = 0; i < 8; ++i)
        emit_row(r[i], r[i + 1], r[i + 2], oplane + (size_t)(h0 + i) * W + c0);

    __builtin_amdgcn_sched_barrier(0);  // don't hoist stage-2 loads (VGPR)

    // ---- Stage 2: rows h0+7 .. h0+16, outputs h0+8 .. h0+15 ----
    // s[i] = row h0+7+i ; s[0],s[1] already live as r[8],r[9].
    float s[10][6];
#pragma unroll
    for (int j = 0; j < 6; ++j) { s[0][j] = r[8][j]; s[1][j] = r[9][j]; }
#pragma unroll
    for (int i = 2; i < 10; ++i) load_row(s[i], plane, h0 + 7 + i, c0);

#pragma unroll
    for (int i = 0; i < 8; ++i)
        emit_row(s[i], s[i + 1], s[i + 2], oplane + (size_t)(h0 + 8 + i) * W + c0);
}

extern "C" void kernel_launch(void* const* d_in, const int* in_sizes, int n_in,
                              void* d_out, int out_size, void* d_ws, size_t ws_size,
                              hipStream_t stream) {
    const float* x = (const float*)d_in[0];
    float* out = (float*)d_out;
    // 16*3 planes * 32 row-blocks * 128 groups = 196,608 threads -> 768 blocks
    constexpr int threads = 256;
    constexpr int total = 16 * 3 * (512 / ROWS) * (512 / 4);
    median_blur_kernel<<<total / threads, threads, 0, stream>>>(x, out);
}

// Round 6
// 21.079 us; speedup vs baseline: 1.6883x; 1.6883x over previous
//
#include <hip/hip_runtime.h>

// Median blur 3x3, zero padding, lower median (== true median for 9 elems).
// x: (16, 3, 512, 512) float32 contiguous. Out same shape/dtype.
//
// R6: R5 post-mortem showed FETCH is already ~1.0x ideal (L2 absorbs halos)
// and the limiter is latency hiding. So: ROWS=4 preload-all (6-row window,
// ~55 VGPRs, launch_bounds(256,8) -> 8 waves/SIMD), 3072 blocks = 12/CU,
// occupancy -> ~100%. No sched_barrier, no big arrays, no spills.

typedef float vf4 __attribute__((ext_vector_type(4)));

__device__ __forceinline__ void s2(float& a, float& b) {
    float t = fminf(a, b);
    b = fmaxf(a, b);
    a = t;
}
__device__ __forceinline__ float max3(float a, float b, float c) {
    return fmaxf(fmaxf(a, b), c);
}
__device__ __forceinline__ float min3(float a, float b, float c) {
    return fminf(fminf(a, b), c);
}
__device__ __forceinline__ float med3(float a, float b, float c) {
    return fmaxf(fminf(a, b), fminf(fmaxf(a, b), c));
}

constexpr int ROWS = 4;  // output rows per thread

__global__ __launch_bounds__(256, 8) void median_blur_kernel(
        const float* __restrict__ x, float* __restrict__ out) {
    constexpr int W = 512, H = 512, W4 = W / 4;   // 128 groups/row
    constexpr int RB = H / ROWS;                  // 128 row-blocks

    // Bijective XCD-chunked swizzle (gridDim.x == 3072, divisible by 8):
    // consecutive bids (vertically adjacent strips) share an XCD L2.
    int cpx = gridDim.x >> 3;
    int bid = (blockIdx.x & 7) * cpx + (blockIdx.x >> 3);

    int gid = bid * blockDim.x + threadIdx.x;
    int w4 = gid & (W4 - 1);
    int rb = (gid >> 7) & (RB - 1);
    int bc = gid >> 14;

    const float* plane = x + (size_t)bc * H * W;
    float* oplane = out + (size_t)bc * H * W;
    int c0 = w4 * 4;
    int h0 = rb * ROWS;

    // Preload all ROWS+2 = 6 halo rows; all loads issue before any use.
    float r[ROWS + 2][6];
#pragma unroll
    for (int i = 0; i < ROWS + 2; ++i) {
        int rr = h0 - 1 + i;
        if (rr >= 0 && rr < H) {
            const float* p = plane + rr * W + c0;
            vf4 v = *reinterpret_cast<const vf4*>(p);
            r[i][1] = v.x; r[i][2] = v.y; r[i][3] = v.z; r[i][4] = v.w;
            r[i][0] = (c0 > 0)     ? p[-1] : 0.0f;
            r[i][5] = (c0 + 4 < W) ? p[4]  : 0.0f;
        } else {
            r[i][0] = r[i][1] = r[i][2] = 0.0f;
            r[i][3] = r[i][4] = r[i][5] = 0.0f;
        }
    }

#pragma unroll
    for (int i = 0; i < ROWS; ++i) {
        // Sort the 6 columns of 3 (lo <= mi <= hi), shared across 4 outputs.
        float lo[6], mi[6], hi[6];
#pragma unroll
        for (int j = 0; j < 6; ++j) {
            float a = r[i][j], b = r[i + 1][j], c = r[i + 2][j];
            s2(b, c); s2(a, c); s2(a, b);
            lo[j] = a; mi[j] = b; hi[j] = c;
        }

        vf4 o;
        o.x = med3(max3(lo[0], lo[1], lo[2]), med3(mi[0], mi[1], mi[2]), min3(hi[0], hi[1], hi[2]));
        o.y = med3(max3(lo[1], lo[2], lo[3]), med3(mi[1], mi[2], mi[3]), min3(hi[1], hi[2], hi[3]));
        o.z = med3(max3(lo[2], lo[3], lo[4]), med3(mi[2], mi[3], mi[4]), min3(hi[2], hi[3], hi[4]));
        o.w = med3(max3(lo[3], lo[4], lo[5]), med3(mi[3], mi[4], mi[5]), min3(hi[3], hi[4], hi[5]));

        float* po = oplane + (size_t)(h0 + i) * W + c0;
        __builtin_nontemporal_store(o, reinterpret_cast<vf4*>(po));
    }
}

extern "C" void kernel_launch(void* const* d_in, const int* in_sizes, int n_in,
                              void* d_out, int out_size, void* d_ws, size_t ws_size,
                              hipStream_t stream) {
    const float* x = (const float*)d_in[0];
    float* out = (float*)d_out;
    // 16*3 planes * 128 row-blocks * 128 groups = 786,432 threads -> 3072 blocks
    constexpr int threads = 256;
    constexpr int total = 16 * 3 * (512 / ROWS) * (512 / 4);
    median_blur_kernel<<<total / threads, threads, 0, stream>>>(x, out);
}